// Round 9
// baseline (747.067 us; speedup 1.0000x reference)
//
#include <hip/hip_runtime.h>
#include <hip/hip_bf16.h>

#define B_DIM 512
#define T_DIM 512
#define IND 64
#define WIDTH 128
#define GAMMA 0.01f
#define EPS 0.01f

// ---------------------------------------------------------------------------
// Kernel 1: projection  out[m][w] = b[w] + sum_i x[m][i] * V[i][w]
// (unchanged: near BW roofline)
// ---------------------------------------------------------------------------
#define PJ_ROWS 16
#define PJ_NT ((B_DIM * T_DIM) / PJ_ROWS)  // 16384

__global__ __launch_bounds__(256) void proj_kernel(
    const float* __restrict__ x, const float* __restrict__ V,
    const float* __restrict__ bias, float* __restrict__ out) {
  __shared__ __align__(16) float xs[PJ_ROWS * IND];  // 4 KB

  const int tid = threadIdx.x;
  const int c2 = (tid & 63) * 2;
  const int rh = tid >> 6;

  float2 Vreg[IND];
#pragma unroll
  for (int k = 0; k < IND; ++k)
    Vreg[k] = *(const float2*)(V + k * WIDTH + c2);
  const float2 bb = *(const float2*)(bias + c2);

  for (int tile = blockIdx.x; tile < PJ_NT; tile += gridDim.x) {
    const size_t m0 = (size_t)tile * PJ_ROWS;
    __syncthreads();
#pragma unroll
    for (int q = 0; q < 4; ++q)
      xs[tid + 256 * q] = x[m0 * IND + tid + 256 * q];
    __syncthreads();

    float2 acc0 = bb, acc1 = bb, acc2 = bb, acc3 = bb;
#pragma unroll
    for (int k4 = 0; k4 < IND / 4; ++k4) {
      float4 xv0 = ((const float4*)&xs[(rh + 0) * IND])[k4];
      float4 xv1 = ((const float4*)&xs[(rh + 4) * IND])[k4];
      float4 xv2 = ((const float4*)&xs[(rh + 8) * IND])[k4];
      float4 xv3 = ((const float4*)&xs[(rh + 12) * IND])[k4];
#pragma unroll
      for (int j = 0; j < 4; ++j) {
        float2 v = Vreg[4 * k4 + j];
        float e0 = (j == 0) ? xv0.x : (j == 1) ? xv0.y : (j == 2) ? xv0.z : xv0.w;
        float e1 = (j == 0) ? xv1.x : (j == 1) ? xv1.y : (j == 2) ? xv1.z : xv1.w;
        float e2 = (j == 0) ? xv2.x : (j == 1) ? xv2.y : (j == 2) ? xv2.z : xv2.w;
        float e3 = (j == 0) ? xv3.x : (j == 1) ? xv3.y : (j == 2) ? xv3.z : xv3.w;
        acc0.x += e0 * v.x; acc0.y += e0 * v.y;
        acc1.x += e1 * v.x; acc1.y += e1 * v.y;
        acc2.x += e2 * v.x; acc2.y += e2 * v.y;
        acc3.x += e3 * v.x; acc3.y += e3 * v.y;
      }
    }
    *(float2*)(out + (m0 + rh + 0) * WIDTH + c2) = acc0;
    *(float2*)(out + (m0 + rh + 4) * WIDTH + c2) = acc1;
    *(float2*)(out + (m0 + rh + 8) * WIDTH + c2) = acc2;
    *(float2*)(out + (m0 + rh + 12) * WIDTH + c2) = acc3;
  }
}

// ---------------------------------------------------------------------------
// Kernel 2: recurrence, SINGLE-WAVE-AUTONOMOUS rows — zero barriers.
// 512 blocks x 64 threads (1 wave = 1 batch row). Lane l owns cols 2l,2l+1:
// A'[:, 2l:2l+2] in 256 VGPRs (gamma folded into diagonal). Per step the
// lane writes its 2 new state floats to LDS and reads the full 128-float
// state back as uniform b128 broadcasts — same-wave LDS ops are in-order on
// the DS pipe and guarded by lgkmcnt, so NO s_barrier and a SINGLE buffer
// (program order: step-t reads precede step-t writes). No split-k -> zero
// cross-lane reduce ops. Dot via packed float2 FMAs. Rationale: R2-R8 all
// pinned at ~1200 cy/step independent of waves/SIMD and LDS-op count; the
// invariant was the multi-wave barrier + cross-wave LDS round trip in the
// serial chain. This removes both.
// ---------------------------------------------------------------------------
typedef __attribute__((ext_vector_type(2))) float f32x2;

__global__ __launch_bounds__(64) void rnn_kernel(
    const float* __restrict__ W, const float* __restrict__ init,
    float* __restrict__ out, float* __restrict__ finals) {
  __shared__ __align__(16) float sL[WIDTH];  // 512 B, single buffer
  const int b = blockIdx.x;
  const int lane = threadIdx.x;  // 0..63
  const int c0 = 2 * lane;

  // Areg[k] = (A'[k][c0], A'[k][c0+1]),  A' = W - W^T - gamma*I
  f32x2 Areg[WIDTH];
#pragma unroll
  for (int k = 0; k < WIDTH; ++k) {
    float2 wr = *(const float2*)(W + (size_t)k * WIDTH + c0);  // W[k][c0..c0+1]
    float a0 = wr.x - W[(size_t)c0 * WIDTH + k];
    float a1 = wr.y - W[(size_t)(c0 + 1) * WIDTH + k];
    if (k == c0) a0 -= GAMMA;
    if (k == c0 + 1) a1 -= GAMMA;
    Areg[k] = (f32x2){a0, a1};
  }

  float2 s2 = *(const float2*)(init + (size_t)b * WIDTH + c0);
  f32x2 s = (f32x2){s2.x, s2.y};
  *(float2*)&sL[c0] = s2;  // ds_write_b64; same-wave ordering, no barrier

  float* outc = out + (size_t)b * T_DIM * WIDTH + c0;
  float2 u0 = *(const float2*)(outc);
  float2 u1 = *(const float2*)(outc + WIDTH);

#pragma unroll 1
  for (int t = 0; t < T_DIM; ++t) {
    const float2 u = u0;
    u0 = u1;
    const int tp = (t + 2 < T_DIM) ? t + 2 : T_DIM - 1;  // clamped (branchless)
    u1 = *(const float2*)(outc + (size_t)tp * WIDTH);

    const float4* sp = (const float4*)sL;
    f32x2 acc0 = {0.f, 0.f}, acc1 = {0.f, 0.f};
    f32x2 acc2 = {0.f, 0.f}, acc3 = {0.f, 0.f};
#pragma unroll
    for (int k4 = 0; k4 < WIDTH / 4; ++k4) {
      float4 sv = sp[k4];  // uniform address -> LDS broadcast
      acc0 = __builtin_elementwise_fma((f32x2){sv.x, sv.x}, Areg[4 * k4 + 0], acc0);
      acc1 = __builtin_elementwise_fma((f32x2){sv.y, sv.y}, Areg[4 * k4 + 1], acc1);
      acc2 = __builtin_elementwise_fma((f32x2){sv.z, sv.z}, Areg[4 * k4 + 2], acc2);
      acc3 = __builtin_elementwise_fma((f32x2){sv.w, sv.w}, Areg[4 * k4 + 3], acc3);
    }
    f32x2 dot = (acc0 + acc1) + (acc2 + acc3);

    // f = dot + u (gamma already in A'); tanh(f) = 1 - 2/(exp(2f)+1)
    const float f0 = dot.x + u.x;
    const float f1 = dot.y + u.y;
    const float e0 = __expf(2.0f * f0);
    const float e1 = __expf(2.0f * f1);
    const float th0 = fmaf(-2.0f, __builtin_amdgcn_rcpf(e0 + 1.0f), 1.0f);
    const float th1 = fmaf(-2.0f, __builtin_amdgcn_rcpf(e1 + 1.0f), 1.0f);
    s.x = fmaf(EPS, th0, s.x);
    s.y = fmaf(EPS, th1, s.y);

    const float2 ns = make_float2(s.x, s.y);
    *(float2*)(outc + (size_t)t * WIDTH) = ns;  // overwrite u slot (coalesced)
    *(float2*)&sL[c0] = ns;  // ds_write_b64: reads of step t already issued
  }

  *(float2*)(finals + (size_t)b * WIDTH + c0) = make_float2(s.x, s.y);
}

extern "C" void kernel_launch(void* const* d_in, const int* in_sizes, int n_in,
                              void* d_out, int out_size, void* d_ws,
                              size_t ws_size, hipStream_t stream) {
  const float* x = (const float*)d_in[0];
  const float* init = (const float*)d_in[1];
  const float* W = (const float*)d_in[2];
  const float* V = (const float*)d_in[3];
  const float* bias = (const float*)d_in[4];

  float* out = (float*)d_out;
  float* finals = out + (size_t)B_DIM * T_DIM * WIDTH;

  proj_kernel<<<2048, 256, 0, stream>>>(x, V, bias, out);
  rnn_kernel<<<B_DIM, 64, 0, stream>>>(W, init, out, finals);
}

// Round 10
// 337.049 us; speedup vs baseline: 2.2165x; 2.2165x over previous
//
#include <hip/hip_runtime.h>
#include <hip/hip_bf16.h>

#define B_DIM 512
#define T_DIM 512
#define IND 64
#define WIDTH 128
#define GAMMA 0.01f
#define EPS 0.01f

// ---------------------------------------------------------------------------
// Kernel 1: projection  out[m][w] = b[w] + sum_i x[m][i] * V[i][w]
// (unchanged: near BW roofline)
// ---------------------------------------------------------------------------
#define PJ_ROWS 16
#define PJ_NT ((B_DIM * T_DIM) / PJ_ROWS)  // 16384

__global__ __launch_bounds__(256) void proj_kernel(
    const float* __restrict__ x, const float* __restrict__ V,
    const float* __restrict__ bias, float* __restrict__ out) {
  __shared__ __align__(16) float xs[PJ_ROWS * IND];  // 4 KB

  const int tid = threadIdx.x;
  const int c2 = (tid & 63) * 2;
  const int rh = tid >> 6;

  float2 Vreg[IND];
#pragma unroll
  for (int k = 0; k < IND; ++k)
    Vreg[k] = *(const float2*)(V + k * WIDTH + c2);
  const float2 bb = *(const float2*)(bias + c2);

  for (int tile = blockIdx.x; tile < PJ_NT; tile += gridDim.x) {
    const size_t m0 = (size_t)tile * PJ_ROWS;
    __syncthreads();
#pragma unroll
    for (int q = 0; q < 4; ++q)
      xs[tid + 256 * q] = x[m0 * IND + tid + 256 * q];
    __syncthreads();

    float2 acc0 = bb, acc1 = bb, acc2 = bb, acc3 = bb;
#pragma unroll
    for (int k4 = 0; k4 < IND / 4; ++k4) {
      float4 xv0 = ((const float4*)&xs[(rh + 0) * IND])[k4];
      float4 xv1 = ((const float4*)&xs[(rh + 4) * IND])[k4];
      float4 xv2 = ((const float4*)&xs[(rh + 8) * IND])[k4];
      float4 xv3 = ((const float4*)&xs[(rh + 12) * IND])[k4];
#pragma unroll
      for (int j = 0; j < 4; ++j) {
        float2 v = Vreg[4 * k4 + j];
        float e0 = (j == 0) ? xv0.x : (j == 1) ? xv0.y : (j == 2) ? xv0.z : xv0.w;
        float e1 = (j == 0) ? xv1.x : (j == 1) ? xv1.y : (j == 2) ? xv1.z : xv1.w;
        float e2 = (j == 0) ? xv2.x : (j == 1) ? xv2.y : (j == 2) ? xv2.z : xv2.w;
        float e3 = (j == 0) ? xv3.x : (j == 1) ? xv3.y : (j == 2) ? xv3.z : xv3.w;
        acc0.x += e0 * v.x; acc0.y += e0 * v.y;
        acc1.x += e1 * v.x; acc1.y += e1 * v.y;
        acc2.x += e2 * v.x; acc2.y += e2 * v.y;
        acc3.x += e3 * v.x; acc3.y += e3 * v.y;
      }
    }
    *(float2*)(out + (m0 + rh + 0) * WIDTH + c2) = acc0;
    *(float2*)(out + (m0 + rh + 4) * WIDTH + c2) = acc1;
    *(float2*)(out + (m0 + rh + 8) * WIDTH + c2) = acc2;
    *(float2*)(out + (m0 + rh + 12) * WIDTH + c2) = acc3;
  }
}

// ---------------------------------------------------------------------------
// Kernel 2: recurrence — ncols=4 x ksplit=8 (the untried cell).
// DS-pipe model: ds_wave_instrs/CU-step = 128/ncols regardless of ksplit.
// R3 (ncols=2, 64 instrs) was DS-pipe-bound; R4 (ncols=4, 32 instrs) starved
// on occupancy (1 wave/SIMD). This config: 256 thr/block = 4 waves (2/SIMD,
// R3's hiding) AND ncols=4 (R4's DS traffic). ksplit=8 reduce is pure VALU:
// xor1 + xor2 quad_perm DPP make values quad-uniform, then row_half_mirror
// (xor 7) delivers the xor-4 exchange. Stagger ri=(j+kc)&3 -> max 2-way bank
// aliasing (free, m136). Double-buffered state, lgkm-only barrier, depth-2
// u prefetch, all-lane u loads (L2 absorbs 8x redundancy), kc==0 stores.
// ---------------------------------------------------------------------------
#define LDS_BARRIER() asm volatile("s_waitcnt lgkmcnt(0)\n\ts_barrier" ::: "memory")

template <int CTRL>
__device__ __forceinline__ float dpp_mov(float x) {
  return __int_as_float(
      __builtin_amdgcn_update_dpp(0, __float_as_int(x), CTRL, 0xf, 0xf, true));
}

__global__ __launch_bounds__(256) void rnn_kernel(
    const float* __restrict__ W, const float* __restrict__ init,
    float* __restrict__ out, float* __restrict__ finals) {
  __shared__ __align__(16) float sL[2][WIDTH];
  const int b = blockIdx.x;
  const int tid = threadIdx.x;
  const int kc = tid & 7;    // k-chunk, lane bits 0-2
  const int c4 = tid >> 3;   // 0..31 column quad
  const int c0 = 4 * c4;     // columns c0..c0+3

  // Areg[col][4j+m] = A'[kc*16 + ((j+kc)&3)*4 + m][c0+col]
  // A' = W - W^T - gamma*I (stagger baked in; reg indices compile-time)
  float Areg[4][16];
  {
    const int k0 = kc * 16;
#pragma unroll
    for (int j = 0; j < 4; ++j) {
      const int ri = (j + kc) & 3;  // runtime, addresses only
      const int k = k0 + ri * 4;
#pragma unroll
      for (int col = 0; col < 4; ++col) {
        const int cc = c0 + col;
        float4 wr = *(const float4*)(W + (size_t)cc * WIDTH + k);  // W[cc][k..]
        float a0 = W[(size_t)(k + 0) * WIDTH + cc] - wr.x;
        float a1 = W[(size_t)(k + 1) * WIDTH + cc] - wr.y;
        float a2 = W[(size_t)(k + 2) * WIDTH + cc] - wr.z;
        float a3 = W[(size_t)(k + 3) * WIDTH + cc] - wr.w;
        if (k + 0 == cc) a0 -= GAMMA;
        if (k + 1 == cc) a1 -= GAMMA;
        if (k + 2 == cc) a2 -= GAMMA;
        if (k + 3 == cc) a3 -= GAMMA;
        Areg[col][4 * j + 0] = a0;
        Areg[col][4 * j + 1] = a1;
        Areg[col][4 * j + 2] = a2;
        Areg[col][4 * j + 3] = a3;
      }
    }
  }

  float4 s = *(const float4*)(init + (size_t)b * WIDTH + c0);
  if (kc == 0) *(float4*)&sL[0][c0] = s;
  __syncthreads();

  float* outc = out + (size_t)b * T_DIM * WIDTH + c0;
  float4 u0 = *(const float4*)(outc);
  float4 u1 = *(const float4*)(outc + WIDTH);

#pragma unroll 1
  for (int t = 0; t < T_DIM; ++t) {
    const int p = t & 1;
    const float4 u = u0;
    u0 = u1;
    const int tp = (t + 2 < T_DIM) ? t + 2 : T_DIM - 1;
    u1 = *(const float4*)(outc + (size_t)tp * WIDTH);

    const float4* sp = (const float4*)&sL[p][0];
    float a0[4], a1[4];
#pragma unroll
    for (int col = 0; col < 4; ++col) { a0[col] = 0.f; a1[col] = 0.f; }
#pragma unroll
    for (int j = 0; j < 4; ++j) {
      const int ri = (j + kc) & 3;  // 2-way bank aliasing only (free)
      float4 sv = sp[kc * 4 + ri];
#pragma unroll
      for (int col = 0; col < 4; ++col) {
        a0[col] += sv.x * Areg[col][4 * j + 0];
        a1[col] += sv.y * Areg[col][4 * j + 1];
        a0[col] += sv.z * Areg[col][4 * j + 2];
        a1[col] += sv.w * Areg[col][4 * j + 3];
      }
    }
    float d[4];
#pragma unroll
    for (int col = 0; col < 4; ++col) d[col] = a0[col] + a1[col];
    // 8-way split-k reduce over lane bits 0-2, pure VALU:
    // xor1, xor2 (quad_perm) -> quad-uniform; row_half_mirror (xor7) == xor4
#pragma unroll
    for (int col = 0; col < 4; ++col) d[col] += dpp_mov<0xB1>(d[col]);
#pragma unroll
    for (int col = 0; col < 4; ++col) d[col] += dpp_mov<0x4E>(d[col]);
#pragma unroll
    for (int col = 0; col < 4; ++col) d[col] += dpp_mov<0x141>(d[col]);

    float* sa = (float*)&s;
    const float* ua = (const float*)&u;
#pragma unroll
    for (int col = 0; col < 4; ++col) {
      const float f = d[col] + ua[col];  // gamma folded into A'
      // tanh(f) = 1 - 2/(exp(2f)+1); inf-safe both directions
      const float e = __expf(2.0f * f);
      const float th = fmaf(-2.0f, __builtin_amdgcn_rcpf(e + 1.0f), 1.0f);
      sa[col] = fmaf(EPS, th, sa[col]);
    }

    if (kc == 0) {
      *(float4*)(outc + (size_t)t * WIDTH) = s;  // overwrite u slot
      *(float4*)&sL[p ^ 1][c0] = s;
    }
    LDS_BARRIER();  // lgkm-only drain; globals stay in flight
  }

  if (kc == 0) *(float4*)(finals + (size_t)b * WIDTH + c0) = s;
}

extern "C" void kernel_launch(void* const* d_in, const int* in_sizes, int n_in,
                              void* d_out, int out_size, void* d_ws,
                              size_t ws_size, hipStream_t stream) {
  const float* x = (const float*)d_in[0];
  const float* init = (const float*)d_in[1];
  const float* W = (const float*)d_in[2];
  const float* V = (const float*)d_in[3];
  const float* bias = (const float*)d_in[4];

  float* out = (float*)d_out;
  float* finals = out + (size_t)B_DIM * T_DIM * WIDTH;

  proj_kernel<<<2048, 256, 0, stream>>>(x, V, bias, out);
  rnn_kernel<<<B_DIM, 256, 0, stream>>>(W, init, out, finals);
}

// Round 11
// 272.920 us; speedup vs baseline: 2.7373x; 1.2350x over previous
//
#include <hip/hip_runtime.h>
#include <hip/hip_bf16.h>

#define B_DIM 512
#define T_DIM 512
#define IND 64
#define WIDTH 128
#define GAMMA 0.01f
#define EPS 0.01f

// ---------------------------------------------------------------------------
// Kernel 1: projection  out[m][w] = b[w] + sum_i x[m][i] * V[i][w]
// (unchanged: near BW roofline)
// ---------------------------------------------------------------------------
#define PJ_ROWS 16
#define PJ_NT ((B_DIM * T_DIM) / PJ_ROWS)  // 16384

__global__ __launch_bounds__(256) void proj_kernel(
    const float* __restrict__ x, const float* __restrict__ V,
    const float* __restrict__ bias, float* __restrict__ out) {
  __shared__ __align__(16) float xs[PJ_ROWS * IND];  // 4 KB

  const int tid = threadIdx.x;
  const int c2 = (tid & 63) * 2;
  const int rh = tid >> 6;

  float2 Vreg[IND];
#pragma unroll
  for (int k = 0; k < IND; ++k)
    Vreg[k] = *(const float2*)(V + k * WIDTH + c2);
  const float2 bb = *(const float2*)(bias + c2);

  for (int tile = blockIdx.x; tile < PJ_NT; tile += gridDim.x) {
    const size_t m0 = (size_t)tile * PJ_ROWS;
    __syncthreads();
#pragma unroll
    for (int q = 0; q < 4; ++q)
      xs[tid + 256 * q] = x[m0 * IND + tid + 256 * q];
    __syncthreads();

    float2 acc0 = bb, acc1 = bb, acc2 = bb, acc3 = bb;
#pragma unroll
    for (int k4 = 0; k4 < IND / 4; ++k4) {
      float4 xv0 = ((const float4*)&xs[(rh + 0) * IND])[k4];
      float4 xv1 = ((const float4*)&xs[(rh + 4) * IND])[k4];
      float4 xv2 = ((const float4*)&xs[(rh + 8) * IND])[k4];
      float4 xv3 = ((const float4*)&xs[(rh + 12) * IND])[k4];
#pragma unroll
      for (int j = 0; j < 4; ++j) {
        float2 v = Vreg[4 * k4 + j];
        float e0 = (j == 0) ? xv0.x : (j == 1) ? xv0.y : (j == 2) ? xv0.z : xv0.w;
        float e1 = (j == 0) ? xv1.x : (j == 1) ? xv1.y : (j == 2) ? xv1.z : xv1.w;
        float e2 = (j == 0) ? xv2.x : (j == 1) ? xv2.y : (j == 2) ? xv2.z : xv2.w;
        float e3 = (j == 0) ? xv3.x : (j == 1) ? xv3.y : (j == 2) ? xv3.z : xv3.w;
        acc0.x += e0 * v.x; acc0.y += e0 * v.y;
        acc1.x += e1 * v.x; acc1.y += e1 * v.y;
        acc2.x += e2 * v.x; acc2.y += e2 * v.y;
        acc3.x += e3 * v.x; acc3.y += e3 * v.y;
      }
    }
    *(float2*)(out + (m0 + rh + 0) * WIDTH + c2) = acc0;
    *(float2*)(out + (m0 + rh + 4) * WIDTH + c2) = acc1;
    *(float2*)(out + (m0 + rh + 8) * WIDTH + c2) = acc2;
    *(float2*)(out + (m0 + rh + 12) * WIDTH + c2) = acc3;
  }
}

// ---------------------------------------------------------------------------
// Kernel 2: recurrence = R3's proven geometry + DEEP u prefetch.
// Theory: every multi-wave config R2-R10 pinned at ~1150-1400 cy/step; the
// invariant is the depth-2 u prefetch giving only 2S slack for an HBM-stream
// load of latency L~2400 cy -> S forced to L/2. Fix: chunked prefetch, U=8,
// two rolling register buffers (uA consumed, uB in flight). Loads for chunk
// tc+16 issue at end of chunk tc -> slack >= 8 steps >> L. Chunk unroll also
// makes the LDS double-buffer parity compile-time.
// 256 thr/block = (colpair cp 0..63, kc 0..3); 2 cols/thread, split-k=4,
// DPP quad reduce, bank-staggered reads (0 conflicts), lgkm-only barrier.
// ---------------------------------------------------------------------------
#define LDS_BARRIER() asm volatile("s_waitcnt lgkmcnt(0)\n\ts_barrier" ::: "memory")

template <int CTRL>
__device__ __forceinline__ float dpp_mov(float x) {
  return __int_as_float(
      __builtin_amdgcn_update_dpp(0, __float_as_int(x), CTRL, 0xf, 0xf, true));
}

__global__ __launch_bounds__(256) void rnn_kernel(
    const float* __restrict__ W, const float* __restrict__ init,
    float* __restrict__ out, float* __restrict__ finals) {
  __shared__ __align__(16) float sL[2][WIDTH];
  const int b = blockIdx.x;
  const int tid = threadIdx.x;
  const int kc = tid & 3;   // k-chunk, lane bits 0-1
  const int cp = tid >> 2;  // 0..63 column pair
  const int c0 = 2 * cp;

  // Areg[col][4j+m] = A[kc*32 + ((j+2kc)&7)*4 + m][c0+col],  A = W - W^T
  float Areg[2][32];
  {
    const int k0 = kc * 32;
#pragma unroll
    for (int j = 0; j < 8; ++j) {
      const int ri = (j + 2 * kc) & 7;  // runtime, addresses only
      const int k = k0 + ri * 4;
#pragma unroll
      for (int col = 0; col < 2; ++col) {
        const int cc = c0 + col;
        float4 wr = *(const float4*)(W + (size_t)cc * WIDTH + k);
        Areg[col][4 * j + 0] = W[(size_t)(k + 0) * WIDTH + cc] - wr.x;
        Areg[col][4 * j + 1] = W[(size_t)(k + 1) * WIDTH + cc] - wr.y;
        Areg[col][4 * j + 2] = W[(size_t)(k + 2) * WIDTH + cc] - wr.z;
        Areg[col][4 * j + 3] = W[(size_t)(k + 3) * WIDTH + cc] - wr.w;
      }
    }
  }

  float2 s = *(const float2*)(init + (size_t)b * WIDTH + c0);
  if (kc == 0) *(float2*)&sL[0][c0] = s;
  __syncthreads();

  float* outc = out + (size_t)b * T_DIM * WIDTH + c0;

  // Chunked u prefetch: uA = steps tc..tc+7 (consume), uB = tc+8..tc+15.
  float2 uA[8], uB[8];
#pragma unroll
  for (int tt = 0; tt < 8; ++tt) {
    uA[tt] = *(const float2*)(outc + (size_t)tt * WIDTH);
    uB[tt] = *(const float2*)(outc + (size_t)(tt + 8) * WIDTH);
  }

#pragma unroll 1
  for (int tc = 0; tc < T_DIM; tc += 8) {
#pragma unroll
    for (int tt = 0; tt < 8; ++tt) {
      const int p = tt & 1;  // compile-time LDS parity (chunk size even)
      const float2 u = uA[tt];

      const float4* sp = (const float4*)&sL[p][0];
      float a00 = 0.f, a01 = 0.f, a10 = 0.f, a11 = 0.f;
#pragma unroll
      for (int j = 0; j < 8; ++j) {
        const int ri = (j + 2 * kc) & 7;  // bank-staggered (0 conflicts)
        float4 sv = sp[kc * 8 + ri];
        a00 += sv.x * Areg[0][4 * j + 0];
        a01 += sv.y * Areg[0][4 * j + 1];
        a00 += sv.z * Areg[0][4 * j + 2];
        a01 += sv.w * Areg[0][4 * j + 3];
        a10 += sv.x * Areg[1][4 * j + 0];
        a11 += sv.y * Areg[1][4 * j + 1];
        a10 += sv.z * Areg[1][4 * j + 2];
        a11 += sv.w * Areg[1][4 * j + 3];
      }
      float d0 = a00 + a01;
      float d1 = a10 + a11;
      // 4-way split-k sum over lane bits 0-1 via DPP (pure VALU)
      d0 += dpp_mov<0xB1>(d0);
      d1 += dpp_mov<0xB1>(d1);
      d0 += dpp_mov<0x4E>(d0);
      d1 += dpp_mov<0x4E>(d1);

      const float f0 = d0 - GAMMA * s.x + u.x;
      const float f1 = d1 - GAMMA * s.y + u.y;
      // tanh(f) = 1 - 2/(exp(2f)+1); inf-safe both directions
      const float e0 = __expf(2.0f * f0);
      const float e1 = __expf(2.0f * f1);
      const float th0 = fmaf(-2.0f, __builtin_amdgcn_rcpf(e0 + 1.0f), 1.0f);
      const float th1 = fmaf(-2.0f, __builtin_amdgcn_rcpf(e1 + 1.0f), 1.0f);
      s.x = fmaf(EPS, th0, s.x);
      s.y = fmaf(EPS, th1, s.y);

      if (kc == 0) {
        *(float2*)(outc + (size_t)(tc + tt) * WIDTH) = s;  // overwrite u slot
        *(float2*)&sL[p ^ 1][c0] = s;
      }
      LDS_BARRIER();  // lgkm-only drain; globals stay in flight
    }

    // rotate buffers; issue loads for steps tc+16..tc+23 (consumed in >=8
    // steps -> ~8*S cycles of latency slack). Clamp keeps reads in-bounds
    // (clamped values are never consumed: last chunk's uB is unused).
#pragma unroll
    for (int tt = 0; tt < 8; ++tt) {
      uA[tt] = uB[tt];
      const int ts = (tc + 16 + tt < T_DIM) ? tc + 16 + tt : T_DIM - 1;
      uB[tt] = *(const float2*)(outc + (size_t)ts * WIDTH);
    }
  }

  if (kc == 0) *(float2*)(finals + (size_t)b * WIDTH + c0) = s;
}

extern "C" void kernel_launch(void* const* d_in, const int* in_sizes, int n_in,
                              void* d_out, int out_size, void* d_ws,
                              size_t ws_size, hipStream_t stream) {
  const float* x = (const float*)d_in[0];
  const float* init = (const float*)d_in[1];
  const float* W = (const float*)d_in[2];
  const float* V = (const float*)d_in[3];
  const float* bias = (const float*)d_in[4];

  float* out = (float*)d_out;
  float* finals = out + (size_t)B_DIM * T_DIM * WIDTH;

  proj_kernel<<<2048, 256, 0, stream>>>(x, V, bias, out);
  rnn_kernel<<<B_DIM, 256, 0, stream>>>(W, init, out, finals);
}